// Round 20
// baseline (3906.500 us; speedup 1.0000x reference)
//
#include <hip/hip_runtime.h>
#include <hip/hip_bf16.h>

typedef unsigned short u16;
typedef unsigned long long u64;
typedef __attribute__((ext_vector_type(8))) __bf16 bf16x8;
typedef __attribute__((ext_vector_type(4))) float f32x4;
typedef __attribute__((ext_vector_type(4))) unsigned short u16x4;

#define BB 8
#define SS 2048
#define DD 768
#define DFF 3072
#define NL 12
#define ROWS (BB*SS)
#define VOC 32000

__device__ __forceinline__ u16 f2bf(float f){
  union { float f; unsigned u; } v; v.f = f;
  unsigned u = v.u;
  u += 0x7FFF + ((u >> 16) & 1);
  return (u16)(u >> 16);
}
__device__ __forceinline__ float bf2f(u16 b){
  union { unsigned u; float f; } v; v.u = ((unsigned)b) << 16; return v.f;
}

// ---------- setup kernels ----------
__global__ void k_embed(const int* __restrict__ tok, const float4* __restrict__ emb,
                        u16* __restrict__ x){
  int i = blockIdx.x*256 + threadIdx.x;         // groups of 4 elems
  if (i >= ROWS*192) return;
  int row = i/192, c = i - row*192;
  float4 v = emb[(long)tok[row]*192 + c];
  u16x4 o; o[0]=f2bf(v.x); o[1]=f2bf(v.y); o[2]=f2bf(v.z); o[3]=f2bf(v.w);
  *(u16x4*)&x[(long)i*4] = o;
}

__global__ void k_dftD(u16* __restrict__ out){ // [1536][768]: rows<768 cos, >=768 sin
  int i = blockIdx.x*256 + threadIdx.x;
  if (i >= 1536*768) return;
  int n = i/768, k = i - n*768;
  int nn = (n < 768) ? n : n - 768;
  int m = (nn*k) % 768;
  float a = 2.0f*(float)m/768.0f;
  out[i] = f2bf((n < 768) ? cospif(a) : sinpif(a));
}

// folded S-DFT [2048][2048]
__global__ void k_dftS2(u16* __restrict__ out){
  int i = blockIdx.x*256 + threadIdx.x;
  if (i >= 2048*2048) return;
  int t = i >> 11, slot = i & 2047;
  int ss = (slot <= 1024) ? slot : slot - 1024;
  int m = (t*ss) & 2047;
  float a = (float)m * (1.0f/1024.0f);
  out[i] = f2bf((slot <= 1024) ? cospif(a) : -sinpif(a));
}

// ---------- paired LN1 + S-fold (+ optional fused residual from tmp4+bias); x bf16 ----------
// hp: [b*1024 + t] for t in [0,1023]; the t==1024 row goes to h1024[b][768].
template<bool RES>
__global__ void k_ln1_fold(u16* __restrict__ x, const u16* __restrict__ t4,
                           const float* __restrict__ bias,
                           const float* __restrict__ g, const float* __restrict__ b,
                           u16* __restrict__ hp, u16* __restrict__ hm,
                           u16* __restrict__ h1024){
  int gid = blockIdx.x*4 + (threadIdx.x >> 6);
  if (gid >= 8*1025) return;
  int bb = gid/1025, t = gid - bb*1025;
  int u = (2048 - t) & 2047;
  long rt = (long)bb*2048 + t, ru = (long)bb*2048 + u;
  int lane = threadIdx.x & 63;
  float vt[12], vu[12];
  #pragma unroll
  for (int j = 0; j < 12; j++){
    int e = lane + j*64;
    float a0 = bf2f(x[rt*DD + e]), a1 = bf2f(x[ru*DD + e]);
    if (RES){
      float bv = bias[e];
      a0 += bf2f(t4[rt*DD + e]) + bv;
      a1 += bf2f(t4[ru*DD + e]) + bv;
    }
    vt[j] = a0; vu[j] = a1;
  }
  float s0 = 0.f, s1 = 0.f;
  #pragma unroll
  for (int j = 0; j < 12; j++){ s0 += vt[j]; s1 += vu[j]; }
  #pragma unroll
  for (int o = 32; o > 0; o >>= 1){ s0 += __shfl_xor(s0, o); s1 += __shfl_xor(s1, o); }
  float mu0 = s0*(1.0f/768.0f), mu1 = s1*(1.0f/768.0f);
  float q0 = 0.f, q1 = 0.f;
  #pragma unroll
  for (int j = 0; j < 12; j++){ float d0 = vt[j]-mu0, d1 = vu[j]-mu1; q0 += d0*d0; q1 += d1*d1; }
  #pragma unroll
  for (int o = 32; o > 0; o >>= 1){ q0 += __shfl_xor(q0, o); q1 += __shfl_xor(q1, o); }
  float r0 = rsqrtf(q0*(1.0f/768.0f) + 1e-5f);
  float r1 = rsqrtf(q1*(1.0f/768.0f) + 1e-5f);
  const bool single = (t == 0) || (t == 1024);
  u16* hpr = hp + ((long)bb*1024 + t)*DD;
  u16* hmr = hm + ((long)bb*1024 + t)*DD;
  #pragma unroll
  for (int j = 0; j < 12; j++){
    int e = lane + j*64;
    if (RES){ x[rt*DD + e] = f2bf(vt[j]); x[ru*DD + e] = f2bf(vu[j]); }
    float ht = (vt[j]-mu0)*r0*g[e] + b[e];
    float hu = (vu[j]-mu1)*r1*g[e] + b[e];
    if (t == 1024) h1024[bb*DD + e] = f2bf(ht);
    else           hpr[e] = f2bf(single ? ht : ht + hu);
    if (!single) hmr[e] = f2bf(ht - hu);
  }
}

// Ff[b][d][1024] = sum_k h1024[b][k] * cos(2*pi*d*k/768) ; one wave per (b,d)
__global__ void k_slot1024(const u16* __restrict__ h1024, const u16* __restrict__ dftD,
                           u16* __restrict__ Ff){
  int task = blockIdx.x*4 + (threadIdx.x >> 6);     // 8*768 tasks
  if (task >= 8*768) return;
  int b = task/768, d = task - b*768;
  int lane = threadIdx.x & 63;
  float s = 0.f;
  #pragma unroll
  for (int j = 0; j < 12; j++){
    int k = lane + j*64;
    s += bf2f(h1024[b*DD + k]) * bf2f(dftD[(long)d*DD + k]);
  }
  #pragma unroll
  for (int o = 32; o > 0; o >>= 1) s += __shfl_xor(s, o);
  if (lane == 0) Ff[((long)(b*768 + d))*2048 + 1024] = f2bf(s);
}

// ---------- LN2 with fused residual add from tmp2; row-mapped; x bf16 ----------
__global__ void k_ln2_fuse(u16* __restrict__ x, const u16* __restrict__ t2,
                           const float* __restrict__ g, const float* __restrict__ b,
                           u16* __restrict__ h, int rmul, int radd, int nrows){
  int gid = blockIdx.x*4 + (threadIdx.x >> 6);
  if (gid >= nrows) return;
  long row = (long)gid*rmul + radd;
  int lane = threadIdx.x & 63;
  float v[12];
  float s = 0.f;
  #pragma unroll
  for (int j = 0; j < 12; j++){
    int e = lane + j*64;
    long ix = row*DD + e;
    float a = bf2f(x[ix]) + bf2f(t2[ix]);
    v[j] = a; s += a;
  }
  #pragma unroll
  for (int o = 32; o > 0; o >>= 1) s += __shfl_xor(s, o);
  float mu = s * (1.0f/768.0f);
  float q = 0.f;
  #pragma unroll
  for (int j = 0; j < 12; j++){ float d = v[j]-mu; q += d*d; }
  #pragma unroll
  for (int o = 32; o > 0; o >>= 1) q += __shfl_xor(q, o);
  float rs = rsqrtf(q * (1.0f/768.0f) + 1e-5f);
  #pragma unroll
  for (int j = 0; j < 12; j++){
    int e = lane + j*64;
    x[row*DD + e] = f2bf(v[j]);
    h[row*DD + e] = f2bf((v[j]-mu)*rs*g[e] + b[e]);
  }
}

// f32 [R][C] -> bf16 [C][R], both weights in one launch (z=0: W1; z=1: W2)
__global__ void k_transpose2(const float* __restrict__ W1, const float* __restrict__ W2,
                             u16* __restrict__ w1t, u16* __restrict__ w2t){
  __shared__ float t[32][33];
  const float* src; u16* dst; int R, C, bx, by;
  if (blockIdx.z == 0){ src = W1; dst = w1t; R = DD;  C = DFF; bx = blockIdx.x*32; by = blockIdx.y*32; }
  else                { src = W2; dst = w2t; R = DFF; C = DD;  bx = blockIdx.y*32; by = blockIdx.x*32; }
  int tx = threadIdx.x, ty = threadIdx.y;
  #pragma unroll
  for (int i = 0; i < 4; i++) t[ty+i*8][tx] = src[(long)(by+ty+i*8)*C + bx+tx];
  __syncthreads();
  #pragma unroll
  for (int i = 0; i < 4; i++) dst[(long)(bx+ty+i*8)*R + by+tx] = f2bf(t[tx][ty+i*8]);
}

#define EPI_ADDB 1
#define EPI_GELU 2
#define EPI_OUTB 3

// ---------- 256^2 dbuf GEMM (R16-proven), N-first swizzle, M-remap for truncation ----------
#define MFMA_Q(H, G, BF) do { \
  __builtin_amdgcn_s_setprio(1); \
  _Pragma("unroll") \
  for (int mm = 0; mm < 4; ++mm) \
    _Pragma("unroll") \
    for (int nn = 0; nn < 2; ++nn) \
      _Pragma("unroll") \
      for (int ks2 = 0; ks2 < 2; ++ks2) \
        acc[((H)<<2)+mm][((G)<<1)+nn] = __builtin_amdgcn_mfma_f32_16x16x32_bf16( \
            aF[mm][ks2], BF[nn][ks2], acc[((H)<<2)+mm][((G)<<1)+nn], 0, 0, 0); \
  __builtin_amdgcn_s_setprio(0); \
} while(0)

#define GEMM_CORE_BODY \
  f32x4 acc[8][4] = {}; \
  bf16x8 aF[4][2], b0F[2][2], b1F[2][2]; \
  auto stage = [&](int tile){ \
    if (tile >= NT) return; \
    _Pragma("unroll") \
    for (int hh = 0; hh < 4; ++hh){ \
      const int isB   = ((hh + 1) >> 1) & 1; \
      const int rhalf = ((hh >> 1) & 1) << 7; \
      const u16* src = isB ? Bb : Ab; \
      const int rb = (isB ? bn : bm) + rhalf + sRow; \
      const u16* s0 = src + (long)rb * K + (tile << 6) + sCol; \
      u16* d0 = &lds[tile & 1][isB][rhalf + (wave << 3)][0]; \
      __builtin_amdgcn_global_load_lds((__attribute__((address_space(1))) void*)(s0), \
                                       (__attribute__((address_space(3))) void*)(d0), 16, 0, 0); \
      __builtin_amdgcn_global_load_lds((__attribute__((address_space(1))) void*)(s0 + ((long)K << 6)), \
                                       (__attribute__((address_space(3))) void*)(d0 + 64*64), 16, 0, 0); \
    } \
  }; \
  auto readA = [&](int c, int H){ \
    const u16* base = &lds[c][0][(H << 7) + (wm << 6)][0]; \
    _Pragma("unroll") \
    for (int mm = 0; mm < 4; ++mm) \
      _Pragma("unroll") \
      for (int ks2 = 0; ks2 < 2; ++ks2) \
        aF[mm][ks2] = *(const bf16x8*)&base[((mm<<4) + fr)*64 + (((ks2<<5) + fks8) ^ swz)]; \
  }; \
  auto readB = [&](int c, int G, bf16x8 (&bF)[2][2]){ \
    const u16* base = &lds[c][1][(G << 7) + (wn << 5)][0]; \
    _Pragma("unroll") \
    for (int nn = 0; nn < 2; ++nn) \
      _Pragma("unroll") \
      for (int ks2 = 0; ks2 < 2; ++ks2) \
        bF[nn][ks2] = *(const bf16x8*)&base[((nn<<4) + fr)*64 + (((ks2<<5) + fks8) ^ swz)]; \
  }; \
  stage(0); \
  __syncthreads(); \
  for (int T = 0; T < NT; ++T){ \
    stage(T + 1); \
    int c = T & 1; \
    readA(c, 0); readB(c, 0, b0F); \
    MFMA_Q(0, 0, b0F); \
    readB(c, 1, b1F); \
    MFMA_Q(0, 1, b1F); \
    readA(c, 1); \
    MFMA_Q(1, 1, b1F); \
    MFMA_Q(1, 0, b0F); \
    __syncthreads(); \
  }

template<int EPI>
__global__ __launch_bounds__(512, 2)
void k_gemm256(const u16* __restrict__ A, const u16* __restrict__ BT,
               int Nt, int N, int K, int NT, long aBS, long btBS, int rowOffPerZ,
               int mMul, int mAdd,
               u16* __restrict__ X, const float* __restrict__ bias,
               u16* __restrict__ OUT){
  __shared__ __align__(16) u16 lds[2][2][256][64];   // 128 KiB
  const int tid  = threadIdx.x;
  const int wave = tid >> 6, lane = tid & 63;
  const int wm = wave >> 2, wn = wave & 3;

  const int bz = blockIdx.z;
  const u16* Ab = A + (long)bz*aBS;
  const u16* Bb = BT + (long)bz*btBS;
  const int rowOff = bz*rowOffPerZ;

  // XCD-aware swizzle (bypassed when grid.x % 8 != 0), N-first tile order
  const int nwg = gridDim.x;
  const int id  = blockIdx.x;
  const int sw  = ((nwg & 7) == 0) ? ((id & 7) * (nwg >> 3) + (id >> 3)) : id;
  const int bn = (sw % Nt) << 8;
  const int bm = ((sw / Nt) * mMul + mAdd) << 8;

  const int fr   = lane & 15;
  const int fks8 = (lane >> 4) << 3;
  const int swz  = (fr & 7) << 3;
  const int sRow = (wave << 3) + (lane >> 3);
  const int sCol = ((lane & 7) ^ ((lane >> 3) & 7)) << 3;

  GEMM_CORE_BODY

  const int er = (lane >> 4) << 2, ec = lane & 15;
  #pragma unroll
  for (int mi = 0; mi < 8; ++mi){
    int row = bm + ((mi >> 2) << 7) + (wm << 6) + ((mi & 3) << 4) + er;
    #pragma unroll
    for (int ni = 0; ni < 4; ++ni){
      int col = bn + ((ni >> 1) << 7) + (wn << 5) + ((ni & 1) << 4) + ec;
      f32x4 v = acc[mi][ni];
      if constexpr (EPI == EPI_ADDB){
        float bv = bias ? bias[col] : 0.0f;
        #pragma unroll
        for (int r = 0; r < 4; r++){
          long ix = (long)(rowOff + row + r)*N + col;
          X[ix] = f2bf(bf2f(X[ix]) + v[r] + bv);
        }
      } else if constexpr (EPI == EPI_OUTB){
        #pragma unroll
        for (int r = 0; r < 4; r++)
          OUT[(long)(rowOff + row + r)*N + col] = f2bf(v[r]);
      } else { // EPI_GELU
        float bv = bias[col];
        #pragma unroll
        for (int r = 0; r < 4; r++){
          float tt = v[r] + bv;
          OUT[(long)(row + r)*N + col] = f2bf(0.5f*tt*(1.0f + erff(tt*0.70710678118654752f)));
        }
      }
    }
  }
}

// ---------- merged folded GEMM1: "+" (hp@cos, 96 blocks) and "-" (hm@sin, 96) ----------
__global__ __launch_bounds__(512, 2)
void k_gemm1(const u16* __restrict__ hp, const u16* __restrict__ hm,
             const u16* __restrict__ dftD, u16* __restrict__ Ff){
  __shared__ __align__(16) u16 lds[2][2][256][64];
  const int tid  = threadIdx.x;
  const int wave = tid >> 6, lane = tid & 63;
  const int wm = wave >> 2, wn = wave & 3;

  const int K = 768, NT = 12;
  const int nwg = gridDim.x;                 // 192
  const int id  = blockIdx.x;
  int sw  = (id & 7) * (nwg >> 3) + (id >> 3);
  const bool plus = (sw < 96);
  const u16* Ab;
  const u16* Bb;
  if (plus){ Ab = hp; Bb = dftD; }
  else     { sw -= 96; Ab = hm; Bb = dftD + 768*768; }
  const int bn = (sw % 3) << 8;              // N-first: 3 N-tiles per A panel
  const int bm = (sw / 3) << 8;

  const int fr   = lane & 15;
  const int fks8 = (lane >> 4) << 3;
  const int swz  = (fr & 7) << 3;
  const int sRow = (wave << 3) + (lane >> 3);
  const int sCol = ((lane & 7) ^ ((lane >> 3) & 7)) << 3;

  GEMM_CORE_BODY

  const int er = (lane >> 4) << 2, ec = lane & 15;
  #pragma unroll
  for (int mi = 0; mi < 8; ++mi){
    int row = bm + ((mi >> 2) << 7) + (wm << 6) + ((mi & 3) << 4) + er;
    #pragma unroll
    for (int ni = 0; ni < 4; ++ni){
      int col = bn + ((ni >> 1) << 7) + (wn << 5) + ((ni & 1) << 4) + ec;  // = d
      f32x4 v = acc[mi][ni];
      u16x4 pk;
      #pragma unroll
      for (int r = 0; r < 4; r++) pk[r] = f2bf(v[r]);
      int b = row >> 10, t = row & 1023;                 // t multiple of 4
      if (plus){
        u16* dst = Ff + ((long)(b*768 + col))*2048 + t;  // slots 0..1023
        *(u16x4*)dst = pk;
      } else {
        u16* dst = Ff + ((long)(b*768 + col))*2048 + 1024 + t;  // slots 1025..2047
        if (t == 0){ dst[1] = pk[1]; dst[2] = pk[2]; dst[3] = pk[3]; }  // skip slot 1024
        else        *(u16x4*)dst = pk;
      }
    }
  }
}

__global__ void k_logits(const u16* __restrict__ x, const float* __restrict__ Wout,
                         const float* __restrict__ bout, float* __restrict__ out){
  __shared__ float xl[8][768];
  int tid = threadIdx.x;
  for (int i = tid; i < 8*768; i += 256){
    int b = i/768, d = i - b*768;
    xl[b][d] = bf2f(x[((long)(b*2048 + 2047))*768 + d]);
  }
  __syncthreads();
  int v = blockIdx.x*256 + tid;
  float acc[8];
  float bv = bout[v];
  #pragma unroll
  for (int b = 0; b < 8; b++) acc[b] = bv;
  for (int d = 0; d < 768; d++){
    float w = Wout[(long)d*VOC + v];
    #pragma unroll
    for (int b = 0; b < 8; b++) acc[b] += xl[b][d]*w;
  }
  #pragma unroll
  for (int b = 0; b < 8; b++) out[(long)b*VOC + v] = acc[b];
}

extern "C" void kernel_launch(void* const* d_in, const int* in_sizes, int n_in,
                              void* d_out, int out_size, void* d_ws, size_t ws_size,
                              hipStream_t stream){
  const int*   tokens = (const int*)d_in[0];
  const float* embed  = (const float*)d_in[1];
  const float* ln1_g  = (const float*)d_in[2];
  const float* ln1_b  = (const float*)d_in[3];
  const float* ln2_g  = (const float*)d_in[4];
  const float* ln2_b  = (const float*)d_in[5];
  const float* W1     = (const float*)d_in[6];
  const float* b1     = (const float*)d_in[7];
  const float* W2     = (const float*)d_in[8];
  const float* b2     = (const float*)d_in[9];
  const float* Wout   = (const float*)d_in[10];
  const float* bout   = (const float*)d_in[11];
  float* out = (float*)d_out;

  char* p = (char*)d_ws;
  size_t off = 0;
  auto alloc = [&](size_t bytes)->char*{
    char* r = p + off; off += (bytes + 255) & ~(size_t)255; return r;
  };
  u16*   x     = (u16*)  alloc((size_t)ROWS*DD*2);    // bf16 residual stream
  u16*   h     = (u16*)  alloc((size_t)ROWS*DD*2);    // LN2 output bf16
  u16*  gbuf   = (u16*)  alloc((size_t)ROWS*DFF*2);   // MLP hidden; hp/hm/Ff alias
  u16*  tmpO   = (u16*)  alloc((size_t)ROWS*DD*2);    // GEMM2/GEMM4 raw bf16 output (shared)
  u16*  dftD   = (u16*)  alloc((size_t)1536*768*2);
  u16*  dftS2  = (u16*)  alloc((size_t)2048*2048*2);
  u16*  w1t    = (u16*)  alloc((size_t)DFF*DD*2);
  u16*  w2t    = (u16*)  alloc((size_t)DD*DFF*2);
  u16*  h1024  = (u16*)  alloc((size_t)BB*DD*2);      // the t=1024 LN1 rows
  if (off > ws_size) return;
  u16* hp = gbuf;                                    // [8*1024][768]
  u16* hm = gbuf + (size_t)8*1024*768;               // [8*1024][768]
  u16* Ff = hm   + (size_t)8*1024*768;               // [8][768][2048]

  k_dftD<<<(1536*768+255)/256, 256, 0, stream>>>(dftD);
  k_dftS2<<<(2048*2048+255)/256, 256, 0, stream>>>(dftS2);
  k_embed<<<(ROWS*192+255)/256, 256, 0, stream>>>(tokens, (const float4*)embed, x);

  for (int l = 0; l < NL; l++){
    const bool last = (l == NL-1);
    // LN1 (+ fused residual from previous GEMM4 tmpO + bias) + S-axis fold into hp/hm/h1024
    if (l == 0)
      k_ln1_fold<false><<<2050, 256, 0, stream>>>(x, nullptr, nullptr,
          ln1_g + l*DD, ln1_b + l*DD, hp, hm, h1024);
    else
      k_ln1_fold<true><<<2050, 256, 0, stream>>>(x, tmpO, b2 + (l-1)*DD,
          ln1_g + l*DD, ln1_b + l*DD, hp, hm, h1024);
    // folded GEMM1: Ff = [hp@cosD | hm@sinD] written transposed (slots != 1024)
    k_gemm1<<<192, 512, 0, stream>>>(hp, hm, dftD, Ff);
    // Ff slot 1024 from the single t=1024 row
    k_slot1024<<<1536, 256, 0, stream>>>(h1024, dftD, Ff);
    // GEMM2: tmp2 = dftS2 @ Ff (M=2048,N=768,K=2048, batched over 8) -> raw bf16
    if (!last)
      k_gemm256<EPI_OUTB><<<dim3(24, 1, 8), 512, 0, stream>>>(
          dftS2, Ff, 3, 768, 2048, 32, 0, (long)768*2048, 2048, 1, 0,
          nullptr, nullptr, tmpO);
    else  // only M-tile 7 (rows 1792..2047) feeds row 2047
      k_gemm256<EPI_OUTB><<<dim3(3, 1, 8), 512, 0, stream>>>(
          dftS2, Ff, 3, 768, 2048, 32, 0, (long)768*2048, 2048, 1, 7,
          nullptr, nullptr, tmpO);
    // LN2 with fused residual add (x += tmp2)
    if (!last)
      k_ln2_fuse<<<4096, 256, 0, stream>>>(x, tmpO,
          ln2_g + l*DD, ln2_b + l*DD, h, 1, 0, 16384);
    else
      k_ln2_fuse<<<2, 256, 0, stream>>>(x, tmpO,
          ln2_g + l*DD, ln2_b + l*DD, h, 2048, 2047, 8);
    // both weight transposes in one launch
    k_transpose2<<<dim3(96, 24, 2), dim3(32,8), 0, stream>>>(
        W1 + (long)l*DD*DFF, W2 + (long)l*DFF*DD, w1t, w2t);
    // GEMM3: g = gelu(h @ W1 + b1)
    if (!last)
      k_gemm256<EPI_GELU><<<768, 512, 0, stream>>>(
          h, w1t, 12, 3072, 768, 12, 0, 0, 0, 1, 0,
          nullptr, b1 + l*DFF, gbuf);
    else  // only M-tiles {8b+7}
      k_gemm256<EPI_GELU><<<96, 512, 0, stream>>>(
          h, w1t, 12, 3072, 768, 12, 0, 0, 0, 8, 7,
          nullptr, b1 + l*DFF, gbuf);
    // GEMM4: raw bf16 tmpO (residual fused into next LN1); last layer: bf16 RMW on x
    if (!last)
      k_gemm256<EPI_OUTB><<<dim3(192, 1, 1), 512, 0, stream>>>(
          gbuf, w2t, 3, 768, 3072, 48, 0, 0, 0, 1, 0,
          nullptr, nullptr, tmpO);
    else
      k_gemm256<EPI_ADDB><<<dim3(24, 1, 1), 512, 0, stream>>>(
          gbuf, w2t, 3, 768, 3072, 48, 0, 0, 0, 8, 7,
          x, b2 + l*DD, nullptr);
  }
  k_logits<<<VOC/256, 256, 0, stream>>>(x, Wout, bout, out);
}

// Round 21
// 3859.031 us; speedup vs baseline: 1.0123x; 1.0123x over previous
//
#include <hip/hip_runtime.h>
#include <hip/hip_bf16.h>

typedef unsigned short u16;
typedef unsigned long long u64;
typedef __attribute__((ext_vector_type(8))) __bf16 bf16x8;
typedef __attribute__((ext_vector_type(4))) float f32x4;
typedef __attribute__((ext_vector_type(4))) unsigned short u16x4;

#define BB 8
#define SS 2048
#define DD 768
#define DFF 3072
#define NL 12
#define ROWS (BB*SS)
#define VOC 32000

__device__ __forceinline__ u16 f2bf(float f){
  union { float f; unsigned u; } v; v.f = f;
  unsigned u = v.u;
  u += 0x7FFF + ((u >> 16) & 1);
  return (u16)(u >> 16);
}
__device__ __forceinline__ float bf2f(u16 b){
  union { unsigned u; float f; } v; v.u = ((unsigned)b) << 16; return v.f;
}

// ---------- setup kernels ----------
__global__ void k_embed(const int* __restrict__ tok, const float4* __restrict__ emb,
                        u16* __restrict__ x){
  int i = blockIdx.x*256 + threadIdx.x;         // groups of 4 elems
  if (i >= ROWS*192) return;
  int row = i/192, c = i - row*192;
  float4 v = emb[(long)tok[row]*192 + c];
  u16x4 o; o[0]=f2bf(v.x); o[1]=f2bf(v.y); o[2]=f2bf(v.z); o[3]=f2bf(v.w);
  *(u16x4*)&x[(long)i*4] = o;
}

__global__ void k_dftD(u16* __restrict__ out){ // [1536][768]: rows<768 cos, >=768 sin
  int i = blockIdx.x*256 + threadIdx.x;
  if (i >= 1536*768) return;
  int n = i/768, k = i - n*768;
  int nn = (n < 768) ? n : n - 768;
  int m = (nn*k) % 768;
  float a = 2.0f*(float)m/768.0f;
  out[i] = f2bf((n < 768) ? cospif(a) : sinpif(a));
}

// folded S-DFT [2048][2048]
__global__ void k_dftS2(u16* __restrict__ out){
  int i = blockIdx.x*256 + threadIdx.x;
  if (i >= 2048*2048) return;
  int t = i >> 11, slot = i & 2047;
  int ss = (slot <= 1024) ? slot : slot - 1024;
  int m = (t*ss) & 2047;
  float a = (float)m * (1.0f/1024.0f);
  out[i] = f2bf((slot <= 1024) ? cospif(a) : -sinpif(a));
}

// ---------- paired LN1 + S-fold (+ optional fused residual from tmp4+bias); x bf16 ----------
template<bool RES>
__global__ void k_ln1_fold(u16* __restrict__ x, const u16* __restrict__ t4,
                           const float* __restrict__ bias,
                           const float* __restrict__ g, const float* __restrict__ b,
                           u16* __restrict__ hp, u16* __restrict__ hm){
  int gid = blockIdx.x*4 + (threadIdx.x >> 6);
  if (gid >= 8*1025) return;
  int bb = gid/1025, t = gid - bb*1025;
  int u = (2048 - t) & 2047;
  long rt = (long)bb*2048 + t, ru = (long)bb*2048 + u;
  int lane = threadIdx.x & 63;
  float vt[12], vu[12];
  #pragma unroll
  for (int j = 0; j < 12; j++){
    int e = lane + j*64;
    float a0 = bf2f(x[rt*DD + e]), a1 = bf2f(x[ru*DD + e]);
    if (RES){
      float bv = bias[e];
      a0 += bf2f(t4[rt*DD + e]) + bv;
      a1 += bf2f(t4[ru*DD + e]) + bv;
    }
    vt[j] = a0; vu[j] = a1;
  }
  float s0 = 0.f, s1 = 0.f;
  #pragma unroll
  for (int j = 0; j < 12; j++){ s0 += vt[j]; s1 += vu[j]; }
  #pragma unroll
  for (int o = 32; o > 0; o >>= 1){ s0 += __shfl_xor(s0, o); s1 += __shfl_xor(s1, o); }
  float mu0 = s0*(1.0f/768.0f), mu1 = s1*(1.0f/768.0f);
  float q0 = 0.f, q1 = 0.f;
  #pragma unroll
  for (int j = 0; j < 12; j++){ float d0 = vt[j]-mu0, d1 = vu[j]-mu1; q0 += d0*d0; q1 += d1*d1; }
  #pragma unroll
  for (int o = 32; o > 0; o >>= 1){ q0 += __shfl_xor(q0, o); q1 += __shfl_xor(q1, o); }
  float r0 = rsqrtf(q0*(1.0f/768.0f) + 1e-5f);
  float r1 = rsqrtf(q1*(1.0f/768.0f) + 1e-5f);
  const bool single = (t == 0) || (t == 1024);
  u16* hpr = hp + ((long)bb*1280 + t)*DD;
  u16* hmr = hm + ((long)bb*1024 + t)*DD;
  #pragma unroll
  for (int j = 0; j < 12; j++){
    int e = lane + j*64;
    if (RES){ x[rt*DD + e] = f2bf(vt[j]); x[ru*DD + e] = f2bf(vu[j]); }
    float ht = (vt[j]-mu0)*r0*g[e] + b[e];
    float hu = (vu[j]-mu1)*r1*g[e] + b[e];
    hpr[e] = f2bf(single ? ht : ht + hu);
    if (!single) hmr[e] = f2bf(ht - hu);
  }
}

// ---------- LN2 with fused residual add from tmp2; row-mapped; x bf16 ----------
__global__ void k_ln2_fuse(u16* __restrict__ x, const u16* __restrict__ t2,
                           const float* __restrict__ g, const float* __restrict__ b,
                           u16* __restrict__ h, int rmul, int radd, int nrows){
  int gid = blockIdx.x*4 + (threadIdx.x >> 6);
  if (gid >= nrows) return;
  long row = (long)gid*rmul + radd;
  int lane = threadIdx.x & 63;
  float v[12];
  float s = 0.f;
  #pragma unroll
  for (int j = 0; j < 12; j++){
    int e = lane + j*64;
    long ix = row*DD + e;
    float a = bf2f(x[ix]) + bf2f(t2[ix]);
    v[j] = a; s += a;
  }
  #pragma unroll
  for (int o = 32; o > 0; o >>= 1) s += __shfl_xor(s, o);
  float mu = s * (1.0f/768.0f);
  float q = 0.f;
  #pragma unroll
  for (int j = 0; j < 12; j++){ float d = v[j]-mu; q += d*d; }
  #pragma unroll
  for (int o = 32; o > 0; o >>= 1) q += __shfl_xor(q, o);
  float rs = rsqrtf(q * (1.0f/768.0f) + 1e-5f);
  #pragma unroll
  for (int j = 0; j < 12; j++){
    int e = lane + j*64;
    x[row*DD + e] = f2bf(v[j]);
    h[row*DD + e] = f2bf((v[j]-mu)*rs*g[e] + b[e]);
  }
}

// f32 [R][C] -> bf16 [C][R], both weights in one launch (z=0: W1 768x3072; z=1: W2 3072x768)
__global__ void k_transpose2(const float* __restrict__ W1, const float* __restrict__ W2,
                             u16* __restrict__ w1t, u16* __restrict__ w2t){
  __shared__ float t[32][33];
  const float* src; u16* dst; int R, C, bx, by;
  if (blockIdx.z == 0){ src = W1; dst = w1t; R = DD;  C = DFF; bx = blockIdx.x*32; by = blockIdx.y*32; }
  else                { src = W2; dst = w2t; R = DFF; C = DD;  bx = blockIdx.y*32; by = blockIdx.x*32; }
  int tx = threadIdx.x, ty = threadIdx.y;
  #pragma unroll
  for (int i = 0; i < 4; i++) t[ty+i*8][tx] = src[(long)(by+ty+i*8)*C + bx+tx];
  __syncthreads();
  #pragma unroll
  for (int i = 0; i < 4; i++) dst[(long)(bx+ty+i*8)*R + by+tx] = f2bf(t[tx][ty+i*8]);
}

#define EPI_ADDB 1
#define EPI_GELU 2
#define EPI_OUTB 3

// ---------- 256^2 dbuf GEMM (R16-proven), N-first swizzle, M-remap for truncation ----------
#define MFMA_Q(H, G, BF) do { \
  __builtin_amdgcn_s_setprio(1); \
  _Pragma("unroll") \
  for (int mm = 0; mm < 4; ++mm) \
    _Pragma("unroll") \
    for (int nn = 0; nn < 2; ++nn) \
      _Pragma("unroll") \
      for (int ks2 = 0; ks2 < 2; ++ks2) \
        acc[((H)<<2)+mm][((G)<<1)+nn] = __builtin_amdgcn_mfma_f32_16x16x32_bf16( \
            aF[mm][ks2], BF[nn][ks2], acc[((H)<<2)+mm][((G)<<1)+nn], 0, 0, 0); \
  __builtin_amdgcn_s_setprio(0); \
} while(0)

#define GEMM_CORE_BODY \
  f32x4 acc[8][4] = {}; \
  bf16x8 aF[4][2], b0F[2][2], b1F[2][2]; \
  auto stage = [&](int tile){ \
    if (tile >= NT) return; \
    _Pragma("unroll") \
    for (int hh = 0; hh < 4; ++hh){ \
      const int isB   = ((hh + 1) >> 1) & 1; \
      const int rhalf = ((hh >> 1) & 1) << 7; \
      const u16* src = isB ? Bb : Ab; \
      const int rb = (isB ? bn : bm) + rhalf + sRow; \
      const u16* s0 = src + (long)rb * K + (tile << 6) + sCol; \
      u16* d0 = &lds[tile & 1][isB][rhalf + (wave << 3)][0]; \
      __builtin_amdgcn_global_load_lds((__attribute__((address_space(1))) void*)(s0), \
                                       (__attribute__((address_space(3))) void*)(d0), 16, 0, 0); \
      __builtin_amdgcn_global_load_lds((__attribute__((address_space(1))) void*)(s0 + ((long)K << 6)), \
                                       (__attribute__((address_space(3))) void*)(d0 + 64*64), 16, 0, 0); \
    } \
  }; \
  auto readA = [&](int c, int H){ \
    const u16* base = &lds[c][0][(H << 7) + (wm << 6)][0]; \
    _Pragma("unroll") \
    for (int mm = 0; mm < 4; ++mm) \
      _Pragma("unroll") \
      for (int ks2 = 0; ks2 < 2; ++ks2) \
        aF[mm][ks2] = *(const bf16x8*)&base[((mm<<4) + fr)*64 + (((ks2<<5) + fks8) ^ swz)]; \
  }; \
  auto readB = [&](int c, int G, bf16x8 (&bF)[2][2]){ \
    const u16* base = &lds[c][1][(G << 7) + (wn << 5)][0]; \
    _Pragma("unroll") \
    for (int nn = 0; nn < 2; ++nn) \
      _Pragma("unroll") \
      for (int ks2 = 0; ks2 < 2; ++ks2) \
        bF[nn][ks2] = *(const bf16x8*)&base[((nn<<4) + fr)*64 + (((ks2<<5) + fks8) ^ swz)]; \
  }; \
  stage(0); \
  __syncthreads(); \
  for (int T = 0; T < NT; ++T){ \
    stage(T + 1); \
    int c = T & 1; \
    readA(c, 0); readB(c, 0, b0F); \
    MFMA_Q(0, 0, b0F); \
    readB(c, 1, b1F); \
    MFMA_Q(0, 1, b1F); \
    readA(c, 1); \
    MFMA_Q(1, 1, b1F); \
    MFMA_Q(1, 0, b0F); \
    __syncthreads(); \
  }

template<int EPI>
__global__ __launch_bounds__(512, 2)
void k_gemm256(const u16* __restrict__ A, const u16* __restrict__ BT,
               int Nt, int N, int K, int NT, long aBS, long btBS, int rowOffPerZ,
               int mMul, int mAdd,
               u16* __restrict__ X, const float* __restrict__ bias,
               u16* __restrict__ OUT){
  __shared__ __align__(16) u16 lds[2][2][256][64];   // 128 KiB
  const int tid  = threadIdx.x;
  const int wave = tid >> 6, lane = tid & 63;
  const int wm = wave >> 2, wn = wave & 3;

  const int bz = blockIdx.z;
  const u16* Ab = A + (long)bz*aBS;
  const u16* Bb = BT + (long)bz*btBS;
  const int rowOff = bz*rowOffPerZ;

  // XCD-aware swizzle (bypassed when grid.x % 8 != 0), N-first tile order
  const int nwg = gridDim.x;
  const int id  = blockIdx.x;
  const int sw  = ((nwg & 7) == 0) ? ((id & 7) * (nwg >> 3) + (id >> 3)) : id;
  const int bn = (sw % Nt) << 8;
  const int bm = ((sw / Nt) * mMul + mAdd) << 8;

  const int fr   = lane & 15;
  const int fks8 = (lane >> 4) << 3;
  const int swz  = (fr & 7) << 3;
  const int sRow = (wave << 3) + (lane >> 3);
  const int sCol = ((lane & 7) ^ ((lane >> 3) & 7)) << 3;

  GEMM_CORE_BODY

  const int er = (lane >> 4) << 2, ec = lane & 15;
  #pragma unroll
  for (int mi = 0; mi < 8; ++mi){
    int row = bm + ((mi >> 2) << 7) + (wm << 6) + ((mi & 3) << 4) + er;
    #pragma unroll
    for (int ni = 0; ni < 4; ++ni){
      int col = bn + ((ni >> 1) << 7) + (wn << 5) + ((ni & 1) << 4) + ec;
      f32x4 v = acc[mi][ni];
      if constexpr (EPI == EPI_ADDB){
        float bv = bias ? bias[col] : 0.0f;
        #pragma unroll
        for (int r = 0; r < 4; r++){
          long ix = (long)(rowOff + row + r)*N + col;
          X[ix] = f2bf(bf2f(X[ix]) + v[r] + bv);
        }
      } else if constexpr (EPI == EPI_OUTB){
        #pragma unroll
        for (int r = 0; r < 4; r++)
          OUT[(long)(rowOff + row + r)*N + col] = f2bf(v[r]);
      } else { // EPI_GELU
        float bv = bias[col];
        #pragma unroll
        for (int r = 0; r < 4; r++){
          float tt = v[r] + bv;
          OUT[(long)(row + r)*N + col] = f2bf(0.5f*tt*(1.0f + erff(tt*0.70710678118654752f)));
        }
      }
    }
  }
}

// ---------- merged folded GEMM1: "+" (hp@cos, 120 blocks) and "-" (hm@sin, 96) ----------
__global__ __launch_bounds__(512, 2)
void k_gemm1(const u16* __restrict__ hp, const u16* __restrict__ hm,
             const u16* __restrict__ dftD, u16* __restrict__ Ff){
  __shared__ __align__(16) u16 lds[2][2][256][64];
  const int tid  = threadIdx.x;
  const int wave = tid >> 6, lane = tid & 63;
  const int wm = wave >> 2, wn = wave & 3;

  const int K = 768, NT = 12;
  const int nwg = gridDim.x;                 // 216
  const int id  = blockIdx.x;
  int sw  = (id & 7) * (nwg >> 3) + (id >> 3);
  const bool plus = (sw < 120);
  const u16* Ab;
  const u16* Bb;
  if (plus){ Ab = hp; Bb = dftD; }
  else     { sw -= 120; Ab = hm; Bb = dftD + 768*768; }
  const int bn = (sw % 3) << 8;              // N-first: 3 N-tiles per A panel
  const int bm = (sw / 3) << 8;

  const int fr   = lane & 15;
  const int fks8 = (lane >> 4) << 3;
  const int swz  = (fr & 7) << 3;
  const int sRow = (wave << 3) + (lane >> 3);
  const int sCol = ((lane & 7) ^ ((lane >> 3) & 7)) << 3;

  GEMM_CORE_BODY

  const int er = (lane >> 4) << 2, ec = lane & 15;
  #pragma unroll
  for (int mi = 0; mi < 8; ++mi){
    int row = bm + ((mi >> 2) << 7) + (wm << 6) + ((mi & 3) << 4) + er;
    #pragma unroll
    for (int ni = 0; ni < 4; ++ni){
      int col = bn + ((ni >> 1) << 7) + (wn << 5) + ((ni & 1) << 4) + ec;  // = d
      f32x4 v = acc[mi][ni];
      u16x4 pk;
      #pragma unroll
      for (int r = 0; r < 4; r++) pk[r] = f2bf(v[r]);
      if (plus){
        int b = row / 1280, t = row - b*1280;
        u16* dst = Ff + ((long)(b*768 + col))*2048 + t;
        if (t <= 1020)      *(u16x4*)dst = pk;
        else if (t == 1024) dst[0] = pk[0];
      } else {
        int b = row >> 10, t = row & 1023;
        u16* dst = Ff + ((long)(b*768 + col))*2048 + 1024 + t;
        if (t == 0){ dst[1] = pk[1]; dst[2] = pk[2]; dst[3] = pk[3]; }
        else        *(u16x4*)dst = pk;
      }
    }
  }
}

__global__ void k_logits(const u16* __restrict__ x, const float* __restrict__ Wout,
                         const float* __restrict__ bout, float* __restrict__ out){
  __shared__ float xl[8][768];
  int tid = threadIdx.x;
  for (int i = tid; i < 8*768; i += 256){
    int b = i/768, d = i - b*768;
    xl[b][d] = bf2f(x[((long)(b*2048 + 2047))*768 + d]);
  }
  __syncthreads();
  int v = blockIdx.x*256 + tid;
  float acc[8];
  float bv = bout[v];
  #pragma unroll
  for (int b = 0; b < 8; b++) acc[b] = bv;
  for (int d = 0; d < 768; d++){
    float w = Wout[(long)d*VOC + v];
    #pragma unroll
    for (int b = 0; b < 8; b++) acc[b] += xl[b][d]*w;
  }
  #pragma unroll
  for (int b = 0; b < 8; b++) out[(long)b*VOC + v] = acc[b];
}

extern "C" void kernel_launch(void* const* d_in, const int* in_sizes, int n_in,
                              void* d_out, int out_size, void* d_ws, size_t ws_size,
                              hipStream_t stream){
  const int*   tokens = (const int*)d_in[0];
  const float* embed  = (const float*)d_in[1];
  const float* ln1_g  = (const float*)d_in[2];
  const float* ln1_b  = (const float*)d_in[3];
  const float* ln2_g  = (const float*)d_in[4];
  const float* ln2_b  = (const float*)d_in[5];
  const float* W1     = (const float*)d_in[6];
  const float* b1     = (const float*)d_in[7];
  const float* W2     = (const float*)d_in[8];
  const float* b2     = (const float*)d_in[9];
  const float* Wout   = (const float*)d_in[10];
  const float* bout   = (const float*)d_in[11];
  float* out = (float*)d_out;

  char* p = (char*)d_ws;
  size_t off = 0;
  auto alloc = [&](size_t bytes)->char*{
    char* r = p + off; off += (bytes + 255) & ~(size_t)255; return r;
  };
  u16*   x    = (u16*)  alloc((size_t)ROWS*DD*2);    // bf16 residual stream
  u16*   h    = (u16*)  alloc((size_t)ROWS*DD*2);    // LN2 output bf16
  u16*  gbuf  = (u16*)  alloc((size_t)ROWS*DFF*2);   // MLP hidden; hp/hm/Ff alias
  u16*  tmpO  = (u16*)  alloc((size_t)ROWS*DD*2);    // GEMM2/GEMM4 raw bf16 output (shared)
  u16*  dftD  = (u16*)  alloc((size_t)1536*768*2);
  u16*  dftS2 = (u16*)  alloc((size_t)2048*2048*2);
  u16*  w1t   = (u16*)  alloc((size_t)DFF*DD*2);
  u16*  w2t   = (u16*)  alloc((size_t)DD*DFF*2);
  if (off > ws_size) return;
  u16* hp = gbuf;                                    // [8*1280][768]
  u16* hm = gbuf + (size_t)8*1280*768;               // [8*1024][768]
  u16* Ff = hm   + (size_t)8*1024*768;               // [8][768][2048]

  k_dftD<<<(1536*768+255)/256, 256, 0, stream>>>(dftD);
  k_dftS2<<<(2048*2048+255)/256, 256, 0, stream>>>(dftS2);
  k_embed<<<(ROWS*192+255)/256, 256, 0, stream>>>(tokens, (const float4*)embed, x);

  for (int l = 0; l < NL; l++){
    const bool last = (l == NL-1);
    // LN1 (+ fused residual from previous GEMM4 tmpO + bias) + S-axis fold into hp/hm
    if (l == 0)
      k_ln1_fold<false><<<2050, 256, 0, stream>>>(x, nullptr, nullptr,
          ln1_g + l*DD, ln1_b + l*DD, hp, hm);
    else
      k_ln1_fold<true><<<2050, 256, 0, stream>>>(x, tmpO, b2 + (l-1)*DD,
          ln1_g + l*DD, ln1_b + l*DD, hp, hm);
    // folded GEMM1: Ff = [hp@cosD | hm@sinD] written transposed
    k_gemm1<<<216, 512, 0, stream>>>(hp, hm, dftD, Ff);
    // GEMM2: tmp2 = dftS2 @ Ff (M=2048,N=768,K=2048, batched over 8) -> raw bf16
    if (!last)
      k_gemm256<EPI_OUTB><<<dim3(24, 1, 8), 512, 0, stream>>>(
          dftS2, Ff, 3, 768, 2048, 32, 0, (long)768*2048, 2048, 1, 0,
          nullptr, nullptr, tmpO);
    else  // only M-tile 7 (rows 1792..2047) feeds row 2047
      k_gemm256<EPI_OUTB><<<dim3(3, 1, 8), 512, 0, stream>>>(
          dftS2, Ff, 3, 768, 2048, 32, 0, (long)768*2048, 2048, 1, 7,
          nullptr, nullptr, tmpO);
    // LN2 with fused residual add (x += tmp2)
    if (!last)
      k_ln2_fuse<<<4096, 256, 0, stream>>>(x, tmpO,
          ln2_g + l*DD, ln2_b + l*DD, h, 1, 0, 16384);
    else
      k_ln2_fuse<<<2, 256, 0, stream>>>(x, tmpO,
          ln2_g + l*DD, ln2_b + l*DD, h, 2048, 2047, 8);
    // both weight transposes in one launch
    k_transpose2<<<dim3(96, 24, 2), dim3(32,8), 0, stream>>>(
        W1 + (long)l*DD*DFF, W2 + (long)l*DFF*DD, w1t, w2t);
    // GEMM3: g = gelu(h @ W1 + b1)
    if (!last)
      k_gemm256<EPI_GELU><<<768, 512, 0, stream>>>(
          h, w1t, 12, 3072, 768, 12, 0, 0, 0, 1, 0,
          nullptr, b1 + l*DFF, gbuf);
    else  // only M-tiles {8b+7}
      k_gemm256<EPI_GELU><<<96, 512, 0, stream>>>(
          h, w1t, 12, 3072, 768, 12, 0, 0, 0, 8, 7,
          nullptr, b1 + l*DFF, gbuf);
    // GEMM4: raw bf16 tmpO (residual fused into next LN1); last layer: bf16 RMW on x
    if (!last)
      k_gemm256<EPI_OUTB><<<dim3(192, 1, 1), 512, 0, stream>>>(
          gbuf, w2t, 3, 768, 3072, 48, 0, 0, 0, 1, 0,
          nullptr, nullptr, tmpO);
    else
      k_gemm256<EPI_ADDB><<<dim3(24, 1, 1), 512, 0, stream>>>(
          gbuf, w2t, 3, 768, 3072, 48, 0, 0, 0, 8, 7,
          x, b2 + l*DD, nullptr);
  }
  k_logits<<<VOC/256, 256, 0, stream>>>(x, Wout, bout, out);
}